// Round 9
// baseline (114.227 us; speedup 1.0000x reference)
//
#include <hip/hip_runtime.h>
#include <hip/hip_bf16.h>

#define BB 4096
#define TT 200
#define LL 8
#define VV 64
#define CC 16
#define NBERN 32
#define CLIP 20.0f
#define TC 25                       // t per chunk (link)
#define NCH (TT / TC)               // 8 chunks per b
#define TOTW (BB * NCH)             // 32768 link waves
#define WPB 4
#define LBLK (TOTW / WPB)           // 8192 link blocks
#define XF4 (TC * CC / 4)           // 100 float4 of x per chunk
#define ZF4 (TC * LL / 4)           // 50 float4 of z per chunk
#define BUF4T (XF4 + ZF4)           // 150 float4 per wave buffer
#define SEGT 25                     // t per segment (var1)

// ---------------- Phase A: segmented scan, thread-per-(b,segment) ----------------
// Block = 64 threads = 8 b's x 8 segments. Full 8-state per thread in registers;
// no cross-lane ops. A^25 built cooperatively in LDS (explicit ping-pong+barriers);
// combine serial per-b through LDS. Exact linear-scan identity.
__global__ __launch_bounds__(64) void var1_v3(
    const float* __restrict__ eps,        // (B,T,L)
    const float* __restrict__ A,          // (L,L)
    const float* __restrict__ logvar_z1,  // (L)
    const float* __restrict__ beta0,      // (L)
    const float* __restrict__ beta1,      // (L)
    float* __restrict__ zout)             // (B,T,L) in ws
{
    const int tid = threadIdx.x;          // 0..63
    const int bl  = tid >> 3;             // local b 0..7
    const int s   = tid & 7;              // segment 0..7
    const int b   = blockIdx.x * 8 + bl;

    __shared__ __align__(16) float epsS[8 * TT * LL];  // 51.2 KB: eps for 8 b's
    __shared__ float Mb[2][64];
    __shared__ float Pw8[64];
    __shared__ float P[64];                            // A^25 row-major
    __shared__ float zendS[8][8][8];                   // [bl][s][j]
    __shared__ float initS[8][8][8];                   // [bl][s][j]

    // ---- stage eps for this block's 8 b's (coalesced float4) ----
    {
        const float4* src = (const float4*)(eps + (size_t)blockIdx.x * 8 * TT * LL);
        float4* dst = (float4*)epsS;
        for (int i = tid; i < 8 * TT * LL / 4; i += 64) dst[i] = src[i];
    }

    // ---- A^25, cooperative: thread tid owns entry (pi,pj) ----
    const int pi = tid >> 3, pj = tid & 7;
    Mb[0][tid] = A[pi * 8 + pj];
    __syncthreads();
    float v;
    v = 0.f;                                            // A^2 : read 0, write 1
#pragma unroll
    for (int l = 0; l < 8; ++l) v = fmaf(Mb[0][pi*8+l], Mb[0][l*8+pj], v);
    Mb[1][tid] = v; __syncthreads();
    v = 0.f;                                            // A^4 : read 1, write 0
#pragma unroll
    for (int l = 0; l < 8; ++l) v = fmaf(Mb[1][pi*8+l], Mb[1][l*8+pj], v);
    Mb[0][tid] = v; __syncthreads();
    v = 0.f;                                            // A^8 : read 0, write 1 (+copy)
#pragma unroll
    for (int l = 0; l < 8; ++l) v = fmaf(Mb[0][pi*8+l], Mb[0][l*8+pj], v);
    Mb[1][tid] = v; Pw8[tid] = v; __syncthreads();
    v = 0.f;                                            // A^16: read 1, write 0
#pragma unroll
    for (int l = 0; l < 8; ++l) v = fmaf(Mb[1][pi*8+l], Mb[1][l*8+pj], v);
    Mb[0][tid] = v; __syncthreads();
    v = 0.f;                                            // A^24 = A^16 * A^8
#pragma unroll
    for (int l = 0; l < 8; ++l) v = fmaf(Mb[0][pi*8+l], Pw8[l*8+pj], v);
    Mb[1][tid] = v; __syncthreads();
    v = 0.f;                                            // A^25 = A^24 * A
#pragma unroll
    for (int l = 0; l < 8; ++l) v = fmaf(Mb[1][pi*8+l], A[l*8+pj], v);
    P[tid] = v; __syncthreads();

    // ---- per-thread params (wave-uniform -> scalar regs) ----
    float Am[8][8], B0[8], B1[8], SL[8];
#pragma unroll
    for (int l = 0; l < 8; ++l)
#pragma unroll
        for (int jj = 0; jj < 8; ++jj) Am[l][jj] = A[l * 8 + jj];
#pragma unroll
    for (int jj = 0; jj < 8; ++jj) {
        B0[jj] = beta0[jj];
        B1[jj] = beta1[jj];
        SL[jj] = __expf(0.5f * logvar_z1[jj]);
    }

    const float* myeps = epsS + ((bl * TT) + s * SEGT) * LL;  // my segment's rows
    const int k0 = (s == 0) ? 1 : 0;

    // ---- pass 1: segment recurrence (zero init for s>0, true init for s==0) ----
    float z[8];
#pragma unroll
    for (int jj = 0; jj < 8; ++jj) z[jj] = 0.f;
    if (s == 0) {
#pragma unroll
        for (int jj = 0; jj < 8; ++jj) z[jj] = myeps[jj] * SL[jj];
    }
    for (int k = k0; k < SEGT; ++k) {
        const int t = s * SEGT + k;
        const float4 e0 = *(const float4*)(myeps + k * 8);
        const float4 e1 = *(const float4*)(myeps + k * 8 + 4);
        const float ef[8] = {e0.x, e0.y, e0.z, e0.w, e1.x, e1.y, e1.z, e1.w};
        const float tf = (float)t;
        float zn[8];
#pragma unroll
        for (int jj = 0; jj < 8; ++jj) {
            float a = fmaf(B1[jj], tf, B0[jj]) + ef[jj];
#pragma unroll
            for (int l = 0; l < 8; ++l) a = fmaf(z[l], Am[l][jj], a);
            zn[jj] = a;
        }
#pragma unroll
        for (int jj = 0; jj < 8; ++jj) z[jj] = zn[jj];
    }
#pragma unroll
    for (int jj = 0; jj < 8; ++jj) zendS[bl][s][jj] = z[jj];
    __syncthreads();

    // ---- combine: s==0 thread of each b chains E_s = zend_s + E_{s-1} @ A^25 ----
    if (s == 0) {
        float E[8];
#pragma unroll
        for (int jj = 0; jj < 8; ++jj) E[jj] = zendS[bl][0][jj];
        for (int ss = 1; ss < 8; ++ss) {
#pragma unroll
            for (int jj = 0; jj < 8; ++jj) initS[bl][ss][jj] = E[jj];  // init for seg ss
            float En[8];
#pragma unroll
            for (int jj = 0; jj < 8; ++jj) {
                float c = 0.f;
#pragma unroll
                for (int l = 0; l < 8; ++l) c = fmaf(E[l], P[l * 8 + jj], c);
                En[jj] = zendS[bl][ss][jj] + c;
            }
#pragma unroll
            for (int jj = 0; jj < 8; ++jj) E[jj] = En[jj];
        }
    }
    __syncthreads();

    // ---- pass 2: corrected init, recompute and store ----
    float* zb = zout + ((size_t)b * TT + s * SEGT) * LL;
    if (s == 0) {
#pragma unroll
        for (int jj = 0; jj < 8; ++jj) z[jj] = myeps[jj] * SL[jj];
        *(float4*)(zb)     = make_float4(z[0], z[1], z[2], z[3]);
        *(float4*)(zb + 4) = make_float4(z[4], z[5], z[6], z[7]);
    } else {
#pragma unroll
        for (int jj = 0; jj < 8; ++jj) z[jj] = initS[bl][s][jj];
    }
    for (int k = k0; k < SEGT; ++k) {
        const int t = s * SEGT + k;
        const float4 e0 = *(const float4*)(myeps + k * 8);
        const float4 e1 = *(const float4*)(myeps + k * 8 + 4);
        const float ef[8] = {e0.x, e0.y, e0.z, e0.w, e1.x, e1.y, e1.z, e1.w};
        const float tf = (float)t;
        float zn[8];
#pragma unroll
        for (int jj = 0; jj < 8; ++jj) {
            float a = fmaf(B1[jj], tf, B0[jj]) + ef[jj];
#pragma unroll
            for (int l = 0; l < 8; ++l) a = fmaf(z[l], Am[l][jj], a);
            zn[jj] = a;
        }
#pragma unroll
        for (int jj = 0; jj < 8; ++jj) z[jj] = zn[jj];
        *(float4*)(zb + (size_t)k * 8)     = make_float4(z[0], z[1], z[2], z[3]);
        *(float4*)(zb + (size_t)k * 8 + 4) = make_float4(z[4], z[5], z[6], z[7]);
    }
}

// ---------------- Phase B: link map, LDS broadcast + NT stores (R6, passing) ----
__global__ __launch_bounds__(256) void link_nt(
    const float* __restrict__ z,          // (B,T,L) from ws
    const float* __restrict__ u,          // (B,1,V)
    const float* __restrict__ x,          // (B,T,C)
    const float* __restrict__ intercepts, // (V)
    const float* __restrict__ wz,         // (L,V)
    const float* __restrict__ wx,         // (C,V)
    const float* __restrict__ logvar_u,   // (V)
    float* __restrict__ lp_out,           // (B,T,V)
    float* __restrict__ cm_out)           // (B,T,V)
{
    const int w    = threadIdx.x >> 6;
    const int lane = threadIdx.x & 63;
    const int gw   = blockIdx.x * WPB + w;
    const int b    = gw >> 3;             // NCH = 8
    const int t0   = (gw & 7) * TC;
    const int v    = lane;

    __shared__ __align__(16) float4 buf[WPB][BUF4T];   // 9.6 KB/block

    float wxv[CC];
#pragma unroll
    for (int c = 0; c < CC; ++c) wxv[c] = wx[c * VV + v];
    float wzv[LL];
#pragma unroll
    for (int l = 0; l < LL; ++l) wzv[l] = wz[l * VV + v];
    const float base = intercepts[v] + u[(size_t)b * VV + v] * __expf(0.5f * logvar_u[v]);

    // stage chunk (wave-private; coalesced float4)
    const float4* gx4 = (const float4*)(x + ((size_t)b * TT + t0) * CC);
    const float4* gz4 = (const float4*)(z + ((size_t)b * TT + t0) * LL);
    float4* bw = buf[w];
    {
        const int i0 = lane;
        bw[i0] = (i0 < XF4) ? gx4[i0] : gz4[i0 - XF4];
        const int i1 = lane + 64;
        bw[i1] = (i1 < XF4) ? gx4[i1] : gz4[i1 - XF4];
        const int i2 = lane + 128;
        if (i2 < BUF4T) bw[i2] = gz4[i2 - XF4];
    }

    const float4* xs4 = bw;               // x: 4 float4 per t
    const float4* zs4 = bw + XF4;         // z: 2 float4 per t

    float* lp = lp_out + ((size_t)b * TT + t0) * VV + v;
    float* cm = cm_out + ((size_t)b * TT + t0) * VV + v;

    float4 cx0 = xs4[0], cx1 = xs4[1], cx2 = xs4[2], cx3 = xs4[3];
    float4 cz0 = zs4[0], cz1 = zs4[1];

    for (int tt = 0; tt < TC; ++tt) {
        float4 nx0, nx1, nx2, nx3, nz0, nz1;
        if (tt + 1 < TC) {
            nx0 = xs4[(tt + 1) * 4 + 0]; nx1 = xs4[(tt + 1) * 4 + 1];
            nx2 = xs4[(tt + 1) * 4 + 2]; nx3 = xs4[(tt + 1) * 4 + 3];
            nz0 = zs4[(tt + 1) * 2 + 0]; nz1 = zs4[(tt + 1) * 2 + 1];
        }

        float a0 = base, a1 = 0.f, a2 = 0.f, a3 = 0.f;
        a0 = fmaf(cx0.x, wxv[0],  a0); a0 = fmaf(cx0.y, wxv[1],  a0);
        a0 = fmaf(cx0.z, wxv[2],  a0); a0 = fmaf(cx0.w, wxv[3],  a0);
        a1 = fmaf(cx1.x, wxv[4],  a1); a1 = fmaf(cx1.y, wxv[5],  a1);
        a1 = fmaf(cx1.z, wxv[6],  a1); a1 = fmaf(cx1.w, wxv[7],  a1);
        a2 = fmaf(cx2.x, wxv[8],  a2); a2 = fmaf(cx2.y, wxv[9],  a2);
        a2 = fmaf(cx2.z, wxv[10], a2); a2 = fmaf(cx2.w, wxv[11], a2);
        a3 = fmaf(cx3.x, wxv[12], a3); a3 = fmaf(cx3.y, wxv[13], a3);
        a3 = fmaf(cx3.z, wxv[14], a3); a3 = fmaf(cx3.w, wxv[15], a3);
        a0 = fmaf(cz0.x, wzv[0],  a0); a0 = fmaf(cz0.y, wzv[1],  a0);
        a1 = fmaf(cz0.z, wzv[2],  a1); a1 = fmaf(cz0.w, wzv[3],  a1);
        a2 = fmaf(cz1.x, wzv[4],  a2); a2 = fmaf(cz1.y, wzv[5],  a2);
        a3 = fmaf(cz1.z, wzv[6],  a3); a3 = fmaf(cz1.w, wzv[7],  a3);

        float acc = (a0 + a1) + (a2 + a3);
        acc = fminf(fmaxf(acc, -CLIP), CLIP);
        const float cmv = (v < NBERN) ? (1.0f / (1.0f + __expf(-acc)))
                                      : __expf(acc);
        __builtin_nontemporal_store(acc, lp + (size_t)tt * VV);
        __builtin_nontemporal_store(cmv, cm + (size_t)tt * VV);

        cx0 = nx0; cx1 = nx1; cx2 = nx2; cx3 = nx3;
        cz0 = nz0; cz1 = nz1;
    }
}

// ---------------- fallback: fused kernel (if ws too small) ----------------
__global__ __launch_bounds__(256) void vargllvm_fused(
    const float* __restrict__ eps, const float* __restrict__ u,
    const float* __restrict__ x, const float* __restrict__ A,
    const float* __restrict__ logvar_z1, const float* __restrict__ beta0,
    const float* __restrict__ beta1, const float* __restrict__ intercepts,
    const float* __restrict__ wz, const float* __restrict__ wx,
    const float* __restrict__ logvar_u,
    float* __restrict__ linpar_out, float* __restrict__ condmean_out)
{
    const int wave = threadIdx.x >> 6;
    const int lane = threadIdx.x & 63;
    const int b    = blockIdx.x * 4 + wave;
    const int v    = lane;

    float wxv[CC];
#pragma unroll
    for (int c = 0; c < CC; ++c) wxv[c] = wx[c * VV + v];
    float wzv[LL];
#pragma unroll
    for (int l = 0; l < LL; ++l) wzv[l] = wz[l * VV + v];
    const float base = intercepts[v] + u[(size_t)b * VV + v] * __expf(0.5f * logvar_u[v]);

    float Ar[LL][LL];
#pragma unroll
    for (int l = 0; l < LL; ++l)
#pragma unroll
        for (int j = 0; j < LL; ++j) Ar[l][j] = A[l * LL + j];
    float b0[LL], b1[LL];
#pragma unroll
    for (int j = 0; j < LL; ++j) { b0[j] = beta0[j]; b1[j] = beta1[j]; }

    const float* epsb = eps + (size_t)b * TT * LL;
    const float* xb   = x   + (size_t)b * TT * CC;
    float* lp = linpar_out   + (size_t)b * TT * VV + v;
    float* cm = condmean_out + (size_t)b * TT * VV + v;

    float zv[LL];
#pragma unroll
    for (int j = 0; j < LL; ++j) zv[j] = epsb[j] * __expf(0.5f * logvar_z1[j]);

    for (int t = 0; t < TT; ++t) {
        if (t > 0) {
            float zn[LL];
            const float tf = (float)t;
#pragma unroll
            for (int j = 0; j < LL; ++j) {
                float a = fmaf(b1[j], tf, b0[j]) + epsb[t * LL + j];
#pragma unroll
                for (int l = 0; l < LL; ++l) a = fmaf(zv[l], Ar[l][j], a);
                zn[j] = a;
            }
#pragma unroll
            for (int j = 0; j < LL; ++j) zv[j] = zn[j];
        }
        float acc = base;
#pragma unroll
        for (int c = 0; c < CC; ++c) acc = fmaf(xb[t * CC + c], wxv[c], acc);
#pragma unroll
        for (int l = 0; l < LL; ++l) acc = fmaf(zv[l], wzv[l], acc);
        acc = fminf(fmaxf(acc, -CLIP), CLIP);
        float cmv = (v < NBERN) ? (1.0f / (1.0f + __expf(-acc))) : __expf(acc);
        lp[(size_t)t * VV] = acc;
        cm[(size_t)t * VV] = cmv;
    }
}

extern "C" void kernel_launch(void* const* d_in, const int* in_sizes, int n_in,
                              void* d_out, int out_size, void* d_ws, size_t ws_size,
                              hipStream_t stream) {
    const float* eps        = (const float*)d_in[0];
    const float* u          = (const float*)d_in[1];
    const float* x          = (const float*)d_in[2];
    const float* A          = (const float*)d_in[3];
    const float* logvar_z1  = (const float*)d_in[4];
    const float* beta0      = (const float*)d_in[5];
    const float* beta1      = (const float*)d_in[6];
    const float* intercepts = (const float*)d_in[7];
    const float* wz         = (const float*)d_in[8];
    const float* wx         = (const float*)d_in[9];
    const float* logvar_u   = (const float*)d_in[10];

    float* linpar   = (float*)d_out;
    float* condmean = (float*)d_out + (size_t)BB * TT * VV;

    const size_t z_bytes = (size_t)BB * TT * LL * sizeof(float);
    if (ws_size >= z_bytes) {
        float* zws = (float*)d_ws;
        hipLaunchKernelGGL(var1_v3, dim3(BB / 8), dim3(64), 0, stream,
                           eps, A, logvar_z1, beta0, beta1, zws);
        hipLaunchKernelGGL(link_nt, dim3(LBLK), dim3(256), 0, stream,
                           zws, u, x, intercepts, wz, wx, logvar_u, linpar, condmean);
    } else {
        hipLaunchKernelGGL(vargllvm_fused, dim3(BB / 4), dim3(256), 0, stream,
                           eps, u, x, A, logvar_z1, beta0, beta1,
                           intercepts, wz, wx, logvar_u, linpar, condmean);
    }
}

// Round 10
// 103.646 us; speedup vs baseline: 1.1021x; 1.1021x over previous
//
#include <hip/hip_runtime.h>
#include <hip/hip_bf16.h>

#define BB 4096
#define TT 200
#define LL 8
#define VV 64
#define CC 16
#define NBERN 32
#define CLIP 20.0f
#define TC 25                       // t per chunk (link)
#define NCH (TT / TC)               // 8 chunks per b
#define TOTW (BB * NCH)             // 32768 link waves
#define WPB 4
#define LBLK (TOTW / WPB)           // 8192 link blocks
#define XF4 (TC * CC / 4)           // 100 float4 of x per chunk
#define ZF4 (TC * LL / 4)           // 50 float4 of z per chunk
#define BUF4T (XF4 + ZF4)           // 150 float4 per wave buffer
#define SEGT 25                     // t per segment (var1)

// ---------------- Phase A: segmented scan, thread-per-(b,segment), no eps LDS ----
// Block = 64 threads = 8 b's x 8 segments. Full 8-state in registers (R8 math,
// verified). eps read directly from global (800B contiguous stream per thread).
// A^25 built cooperatively in tiny LDS; combine serial per-b through LDS.
__global__ __launch_bounds__(64) void var1_v4(
    const float* __restrict__ eps,        // (B,T,L)
    const float* __restrict__ A,          // (L,L)
    const float* __restrict__ logvar_z1,  // (L)
    const float* __restrict__ beta0,      // (L)
    const float* __restrict__ beta1,      // (L)
    float* __restrict__ zout)             // (B,T,L) in ws
{
    const int tid = threadIdx.x;          // 0..63
    const int bl  = tid >> 3;             // local b 0..7
    const int s   = tid & 7;              // segment 0..7
    const int b   = blockIdx.x * 8 + bl;

    __shared__ float Mb[2][64];
    __shared__ float Pw8[64];
    __shared__ float P[64];               // A^25 row-major
    __shared__ float zendS[8][8][8];      // [bl][s][j]
    __shared__ float initS[8][8][8];      // [bl][s][j]

    // ---- A^25, cooperative: thread tid owns entry (pi,pj) ----
    const int pi = tid >> 3, pj = tid & 7;
    Mb[0][tid] = A[pi * 8 + pj];
    __syncthreads();
    float v;
    v = 0.f;                                            // A^2 : read 0, write 1
#pragma unroll
    for (int l = 0; l < 8; ++l) v = fmaf(Mb[0][pi*8+l], Mb[0][l*8+pj], v);
    Mb[1][tid] = v; __syncthreads();
    v = 0.f;                                            // A^4 : read 1, write 0
#pragma unroll
    for (int l = 0; l < 8; ++l) v = fmaf(Mb[1][pi*8+l], Mb[1][l*8+pj], v);
    Mb[0][tid] = v; __syncthreads();
    v = 0.f;                                            // A^8 : read 0, write 1 (+copy)
#pragma unroll
    for (int l = 0; l < 8; ++l) v = fmaf(Mb[0][pi*8+l], Mb[0][l*8+pj], v);
    Mb[1][tid] = v; Pw8[tid] = v; __syncthreads();
    v = 0.f;                                            // A^16: read 1, write 0
#pragma unroll
    for (int l = 0; l < 8; ++l) v = fmaf(Mb[1][pi*8+l], Mb[1][l*8+pj], v);
    Mb[0][tid] = v; __syncthreads();
    v = 0.f;                                            // A^24 = A^16 * A^8
#pragma unroll
    for (int l = 0; l < 8; ++l) v = fmaf(Mb[0][pi*8+l], Pw8[l*8+pj], v);
    Mb[1][tid] = v; __syncthreads();
    v = 0.f;                                            // A^25 = A^24 * A
#pragma unroll
    for (int l = 0; l < 8; ++l) v = fmaf(Mb[1][pi*8+l], A[l*8+pj], v);
    P[tid] = v; __syncthreads();

    // ---- per-thread params (wave-uniform -> scalar regs) ----
    float Am[8][8], B0[8], B1[8], SL[8];
#pragma unroll
    for (int l = 0; l < 8; ++l)
#pragma unroll
        for (int jj = 0; jj < 8; ++jj) Am[l][jj] = A[l * 8 + jj];
#pragma unroll
    for (int jj = 0; jj < 8; ++jj) {
        B0[jj] = beta0[jj];
        B1[jj] = beta1[jj];
        SL[jj] = __expf(0.5f * logvar_z1[jj]);
    }

    const float* myeps = eps + ((size_t)b * TT + s * SEGT) * LL;  // my segment rows
    const int k0 = (s == 0) ? 1 : 0;

    // ---- pass 1: segment recurrence (zero init for s>0, true init for s==0) ----
    float z[8];
#pragma unroll
    for (int jj = 0; jj < 8; ++jj) z[jj] = 0.f;
    if (s == 0) {
#pragma unroll
        for (int jj = 0; jj < 8; ++jj) z[jj] = myeps[jj] * SL[jj];
    }
#pragma unroll 5
    for (int k = k0; k < SEGT; ++k) {
        const int t = s * SEGT + k;
        const float4 e0 = *(const float4*)(myeps + k * 8);
        const float4 e1 = *(const float4*)(myeps + k * 8 + 4);
        const float ef[8] = {e0.x, e0.y, e0.z, e0.w, e1.x, e1.y, e1.z, e1.w};
        const float tf = (float)t;
        float zn[8];
#pragma unroll
        for (int jj = 0; jj < 8; ++jj) {
            float a = fmaf(B1[jj], tf, B0[jj]) + ef[jj];
#pragma unroll
            for (int l = 0; l < 8; ++l) a = fmaf(z[l], Am[l][jj], a);
            zn[jj] = a;
        }
#pragma unroll
        for (int jj = 0; jj < 8; ++jj) z[jj] = zn[jj];
    }
#pragma unroll
    for (int jj = 0; jj < 8; ++jj) zendS[bl][s][jj] = z[jj];
    __syncthreads();

    // ---- combine: s==0 thread of each b chains E_s = zend_s + E_{s-1} @ A^25 ----
    if (s == 0) {
        float E[8];
#pragma unroll
        for (int jj = 0; jj < 8; ++jj) E[jj] = zendS[bl][0][jj];
        for (int ss = 1; ss < 8; ++ss) {
#pragma unroll
            for (int jj = 0; jj < 8; ++jj) initS[bl][ss][jj] = E[jj];  // init for seg ss
            float En[8];
#pragma unroll
            for (int jj = 0; jj < 8; ++jj) {
                float c = 0.f;
#pragma unroll
                for (int l = 0; l < 8; ++l) c = fmaf(E[l], P[l * 8 + jj], c);
                En[jj] = zendS[bl][ss][jj] + c;
            }
#pragma unroll
            for (int jj = 0; jj < 8; ++jj) E[jj] = En[jj];
        }
    }
    __syncthreads();

    // ---- pass 2: corrected init, recompute and store ----
    float* zb = zout + ((size_t)b * TT + s * SEGT) * LL;
    if (s == 0) {
#pragma unroll
        for (int jj = 0; jj < 8; ++jj) z[jj] = myeps[jj] * SL[jj];
        *(float4*)(zb)     = make_float4(z[0], z[1], z[2], z[3]);
        *(float4*)(zb + 4) = make_float4(z[4], z[5], z[6], z[7]);
    } else {
#pragma unroll
        for (int jj = 0; jj < 8; ++jj) z[jj] = initS[bl][s][jj];
    }
#pragma unroll 5
    for (int k = k0; k < SEGT; ++k) {
        const int t = s * SEGT + k;
        const float4 e0 = *(const float4*)(myeps + k * 8);
        const float4 e1 = *(const float4*)(myeps + k * 8 + 4);
        const float ef[8] = {e0.x, e0.y, e0.z, e0.w, e1.x, e1.y, e1.z, e1.w};
        const float tf = (float)t;
        float zn[8];
#pragma unroll
        for (int jj = 0; jj < 8; ++jj) {
            float a = fmaf(B1[jj], tf, B0[jj]) + ef[jj];
#pragma unroll
            for (int l = 0; l < 8; ++l) a = fmaf(z[l], Am[l][jj], a);
            zn[jj] = a;
        }
#pragma unroll
        for (int jj = 0; jj < 8; ++jj) z[jj] = zn[jj];
        *(float4*)(zb + (size_t)k * 8)     = make_float4(z[0], z[1], z[2], z[3]);
        *(float4*)(zb + (size_t)k * 8 + 4) = make_float4(z[4], z[5], z[6], z[7]);
    }
}

// ---------------- Phase B: link map, LDS broadcast + NT stores (R6, passing) ----
__global__ __launch_bounds__(256) void link_nt(
    const float* __restrict__ z,          // (B,T,L) from ws
    const float* __restrict__ u,          // (B,1,V)
    const float* __restrict__ x,          // (B,T,C)
    const float* __restrict__ intercepts, // (V)
    const float* __restrict__ wz,         // (L,V)
    const float* __restrict__ wx,         // (C,V)
    const float* __restrict__ logvar_u,   // (V)
    float* __restrict__ lp_out,           // (B,T,V)
    float* __restrict__ cm_out)           // (B,T,V)
{
    const int w    = threadIdx.x >> 6;
    const int lane = threadIdx.x & 63;
    const int gw   = blockIdx.x * WPB + w;
    const int b    = gw >> 3;             // NCH = 8
    const int t0   = (gw & 7) * TC;
    const int v    = lane;

    __shared__ __align__(16) float4 buf[WPB][BUF4T];   // 9.6 KB/block

    float wxv[CC];
#pragma unroll
    for (int c = 0; c < CC; ++c) wxv[c] = wx[c * VV + v];
    float wzv[LL];
#pragma unroll
    for (int l = 0; l < LL; ++l) wzv[l] = wz[l * VV + v];
    const float base = intercepts[v] + u[(size_t)b * VV + v] * __expf(0.5f * logvar_u[v]);

    // stage chunk (wave-private; coalesced float4)
    const float4* gx4 = (const float4*)(x + ((size_t)b * TT + t0) * CC);
    const float4* gz4 = (const float4*)(z + ((size_t)b * TT + t0) * LL);
    float4* bw = buf[w];
    {
        const int i0 = lane;
        bw[i0] = (i0 < XF4) ? gx4[i0] : gz4[i0 - XF4];
        const int i1 = lane + 64;
        bw[i1] = (i1 < XF4) ? gx4[i1] : gz4[i1 - XF4];
        const int i2 = lane + 128;
        if (i2 < BUF4T) bw[i2] = gz4[i2 - XF4];
    }

    const float4* xs4 = bw;               // x: 4 float4 per t
    const float4* zs4 = bw + XF4;         // z: 2 float4 per t

    float* lp = lp_out + ((size_t)b * TT + t0) * VV + v;
    float* cm = cm_out + ((size_t)b * TT + t0) * VV + v;

    float4 cx0 = xs4[0], cx1 = xs4[1], cx2 = xs4[2], cx3 = xs4[3];
    float4 cz0 = zs4[0], cz1 = zs4[1];

    for (int tt = 0; tt < TC; ++tt) {
        float4 nx0, nx1, nx2, nx3, nz0, nz1;
        if (tt + 1 < TC) {
            nx0 = xs4[(tt + 1) * 4 + 0]; nx1 = xs4[(tt + 1) * 4 + 1];
            nx2 = xs4[(tt + 1) * 4 + 2]; nx3 = xs4[(tt + 1) * 4 + 3];
            nz0 = zs4[(tt + 1) * 2 + 0]; nz1 = zs4[(tt + 1) * 2 + 1];
        }

        float a0 = base, a1 = 0.f, a2 = 0.f, a3 = 0.f;
        a0 = fmaf(cx0.x, wxv[0],  a0); a0 = fmaf(cx0.y, wxv[1],  a0);
        a0 = fmaf(cx0.z, wxv[2],  a0); a0 = fmaf(cx0.w, wxv[3],  a0);
        a1 = fmaf(cx1.x, wxv[4],  a1); a1 = fmaf(cx1.y, wxv[5],  a1);
        a1 = fmaf(cx1.z, wxv[6],  a1); a1 = fmaf(cx1.w, wxv[7],  a1);
        a2 = fmaf(cx2.x, wxv[8],  a2); a2 = fmaf(cx2.y, wxv[9],  a2);
        a2 = fmaf(cx2.z, wxv[10], a2); a2 = fmaf(cx2.w, wxv[11], a2);
        a3 = fmaf(cx3.x, wxv[12], a3); a3 = fmaf(cx3.y, wxv[13], a3);
        a3 = fmaf(cx3.z, wxv[14], a3); a3 = fmaf(cx3.w, wxv[15], a3);
        a0 = fmaf(cz0.x, wzv[0],  a0); a0 = fmaf(cz0.y, wzv[1],  a0);
        a1 = fmaf(cz0.z, wzv[2],  a1); a1 = fmaf(cz0.w, wzv[3],  a1);
        a2 = fmaf(cz1.x, wzv[4],  a2); a2 = fmaf(cz1.y, wzv[5],  a2);
        a3 = fmaf(cz1.z, wzv[6],  a3); a3 = fmaf(cz1.w, wzv[7],  a3);

        float acc = (a0 + a1) + (a2 + a3);
        acc = fminf(fmaxf(acc, -CLIP), CLIP);
        const float cmv = (v < NBERN) ? (1.0f / (1.0f + __expf(-acc)))
                                      : __expf(acc);
        __builtin_nontemporal_store(acc, lp + (size_t)tt * VV);
        __builtin_nontemporal_store(cmv, cm + (size_t)tt * VV);

        cx0 = nx0; cx1 = nx1; cx2 = nx2; cx3 = nx3;
        cz0 = nz0; cz1 = nz1;
    }
}

// ---------------- fallback: fused kernel (if ws too small) ----------------
__global__ __launch_bounds__(256) void vargllvm_fused(
    const float* __restrict__ eps, const float* __restrict__ u,
    const float* __restrict__ x, const float* __restrict__ A,
    const float* __restrict__ logvar_z1, const float* __restrict__ beta0,
    const float* __restrict__ beta1, const float* __restrict__ intercepts,
    const float* __restrict__ wz, const float* __restrict__ wx,
    const float* __restrict__ logvar_u,
    float* __restrict__ linpar_out, float* __restrict__ condmean_out)
{
    const int wave = threadIdx.x >> 6;
    const int lane = threadIdx.x & 63;
    const int b    = blockIdx.x * 4 + wave;
    const int v    = lane;

    float wxv[CC];
#pragma unroll
    for (int c = 0; c < CC; ++c) wxv[c] = wx[c * VV + v];
    float wzv[LL];
#pragma unroll
    for (int l = 0; l < LL; ++l) wzv[l] = wz[l * VV + v];
    const float base = intercepts[v] + u[(size_t)b * VV + v] * __expf(0.5f * logvar_u[v]);

    float Ar[LL][LL];
#pragma unroll
    for (int l = 0; l < LL; ++l)
#pragma unroll
        for (int j = 0; j < LL; ++j) Ar[l][j] = A[l * LL + j];
    float b0[LL], b1[LL];
#pragma unroll
    for (int j = 0; j < LL; ++j) { b0[j] = beta0[j]; b1[j] = beta1[j]; }

    const float* epsb = eps + (size_t)b * TT * LL;
    const float* xb   = x   + (size_t)b * TT * CC;
    float* lp = linpar_out   + (size_t)b * TT * VV + v;
    float* cm = condmean_out + (size_t)b * TT * VV + v;

    float zv[LL];
#pragma unroll
    for (int j = 0; j < LL; ++j) zv[j] = epsb[j] * __expf(0.5f * logvar_z1[j]);

    for (int t = 0; t < TT; ++t) {
        if (t > 0) {
            float zn[LL];
            const float tf = (float)t;
#pragma unroll
            for (int j = 0; j < LL; ++j) {
                float a = fmaf(b1[j], tf, b0[j]) + epsb[t * LL + j];
#pragma unroll
                for (int l = 0; l < LL; ++l) a = fmaf(zv[l], Ar[l][j], a);
                zn[j] = a;
            }
#pragma unroll
            for (int j = 0; j < LL; ++j) zv[j] = zn[j];
        }
        float acc = base;
#pragma unroll
        for (int c = 0; c < CC; ++c) acc = fmaf(xb[t * CC + c], wxv[c], acc);
#pragma unroll
        for (int l = 0; l < LL; ++l) acc = fmaf(zv[l], wzv[l], acc);
        acc = fminf(fmaxf(acc, -CLIP), CLIP);
        float cmv = (v < NBERN) ? (1.0f / (1.0f + __expf(-acc))) : __expf(acc);
        lp[(size_t)t * VV] = acc;
        cm[(size_t)t * VV] = cmv;
    }
}

extern "C" void kernel_launch(void* const* d_in, const int* in_sizes, int n_in,
                              void* d_out, int out_size, void* d_ws, size_t ws_size,
                              hipStream_t stream) {
    const float* eps        = (const float*)d_in[0];
    const float* u          = (const float*)d_in[1];
    const float* x          = (const float*)d_in[2];
    const float* A          = (const float*)d_in[3];
    const float* logvar_z1  = (const float*)d_in[4];
    const float* beta0      = (const float*)d_in[5];
    const float* beta1      = (const float*)d_in[6];
    const float* intercepts = (const float*)d_in[7];
    const float* wz         = (const float*)d_in[8];
    const float* wx         = (const float*)d_in[9];
    const float* logvar_u   = (const float*)d_in[10];

    float* linpar   = (float*)d_out;
    float* condmean = (float*)d_out + (size_t)BB * TT * VV;

    const size_t z_bytes = (size_t)BB * TT * LL * sizeof(float);
    if (ws_size >= z_bytes) {
        float* zws = (float*)d_ws;
        hipLaunchKernelGGL(var1_v4, dim3(BB / 8), dim3(64), 0, stream,
                           eps, A, logvar_z1, beta0, beta1, zws);
        hipLaunchKernelGGL(link_nt, dim3(LBLK), dim3(256), 0, stream,
                           zws, u, x, intercepts, wz, wx, logvar_u, linpar, condmean);
    } else {
        hipLaunchKernelGGL(vargllvm_fused, dim3(BB / 4), dim3(256), 0, stream,
                           eps, u, x, A, logvar_z1, beta0, beta1,
                           intercepts, wz, wx, logvar_u, linpar, condmean);
    }
}